// Round 9
// baseline (250.915 us; speedup 1.0000x reference)
//
#include <hip/hip_runtime.h>
#include <hip/hip_bf16.h>
#include <stdint.h>

typedef __bf16 bf16x8 __attribute__((ext_vector_type(8)));
typedef float f32x4 __attribute__((ext_vector_type(4)));

#define MAXD 40
#define ND   81
#define CSZ  256
#define HSZ  128
#define WSZ  416
#define HW   (HSZ * WSZ)
#define NCHUNK 8

#define STRL  420      // dwords per L cpair row (416 data + pad; 4*STRL%32==16)
#define STRR  500      // dwords per R cpair row (496 data + pad; 4*STRR%32==16)
#define RBASE 6720     // dword offset of R region (=16*STRL)
#define SHDW  14720    // total Sh dwords (=RBASE+16*STRR) : 58880 B
#define ESTR  420      // epilogue row stride (dwords)

union FragU { uint32_t u[4]; bf16x8 v; };

static __device__ __forceinline__ uint32_t pk2(float a, float b) {
    union { __bf16 h[2]; uint32_t u; } v;
    v.h[0] = (__bf16)a; v.h[1] = (__bf16)b;
    return v.u;
}

// LDS-only drain barrier: global loads/stores stay in flight across it.
static __device__ __forceinline__ void lds_barrier() {
    asm volatile("s_waitcnt lgkmcnt(0)" ::: "memory");
    __builtin_amdgcn_s_barrier();
    __builtin_amdgcn_sched_barrier(0);
}

__global__ __launch_bounds__(512, 4)
void corr_mfma_kernel(const float* __restrict__ left,
                      const float* __restrict__ right,
                      float* __restrict__ out) {
    __shared__ uint32_t Sh[SHDW];   // L[16][420] | R[16][500], bf16 pairs [cpair][w][2]

    const int t   = threadIdx.x;
    const int wv  = t >> 6;      // 0..7
    const int l   = t & 63;
    const int l15 = l & 15;
    const int l4  = l >> 4;      // 0..3
    const int b   = blockIdx.x >> 7;
    const int h   = blockIdx.x & 127;

    const size_t slab = ((size_t)b * CSZ) * HW + (size_t)h * WSZ;
    const float* Lp = left  + slab;
    const float* Rp = right + slab;

    // ---- zero R halo cols once (u+40 in [0,40) and [456,496)) ----
    #pragma unroll
    for (int i = 0; i < 3; ++i) {
        const int idx = i * 512 + t;       // 16 rows x 80 cols = 1280
        if (idx < 1280) {
            const int cp = idx / 80;
            const int k  = idx - 80 * cp;
            const int col = (k < 40) ? k : (k + 416);
            Sh[RBASE + cp * STRR + col] = 0u;
        }
    }

    f32x4 acc[4][6];
    #pragma unroll
    for (int pi = 0; pi < 4; ++pi)
        #pragma unroll
        for (int a = 0; a < 6; ++a)
            acc[pi][a] = (f32x4)0.0f;

    // fragment read bases (dwords); col in dwords == w index
    const int LA = (4 * l4) * STRL + l15;
    const int LB = RBASE + (4 * l4) * STRR + l15;

    for (int ck = 0; ck < NCHUNK; ++ck) {
        const float* Lc = Lp + (size_t)(ck * 32) * HW;
        const float* Rc = Rp + (size_t)(ck * 32) * HW;

        // ---- stage: 16 cpair x 208 wpair items; per item 4x float2 -> 2x ds_write_b64 ----
        #pragma unroll
        for (int i = 0; i < 7; ++i) {
            const int idx = i * 512 + t;
            if (idx < 3328) {
                const int cp = idx / 208;
                const int wp = idx - 208 * cp;
                const float2 a0 = *(const float2*)(Lc + (size_t)(2 * cp) * HW + 2 * wp);
                const float2 a1 = *(const float2*)(Lc + (size_t)(2 * cp + 1) * HW + 2 * wp);
                const float2 b0 = *(const float2*)(Rc + (size_t)(2 * cp) * HW + 2 * wp);
                const float2 b1 = *(const float2*)(Rc + (size_t)(2 * cp + 1) * HW + 2 * wp);
                uint2 lw, rw;
                lw.x = pk2(a0.x, a1.x);  lw.y = pk2(a0.y, a1.y);
                rw.x = pk2(b0.x, b1.x);  rw.y = pk2(b0.y, b1.y);
                *(uint2*)&Sh[cp * STRL + 2 * wp]              = lw;
                *(uint2*)&Sh[RBASE + cp * STRR + 40 + 2 * wp] = rw;
            }
        }

        lds_barrier();   // tile visible

        // ---- banded MFMA: wave owns p = 4*wv + pi; tiles (r = p-5+a, j = 5-a) ----
        bf16x8 bf[4];
        #pragma unroll
        for (int pi = 0; pi < 4; ++pi) {
            const int p  = 4 * wv + pi;
            const int pc = (p > 30) ? 30 : p;
            FragU u;
            #pragma unroll
            for (int i2 = 0; i2 < 4; ++i2)
                u.u[i2] = Sh[LB + i2 * STRR + 16 * pc];
            bf[pi] = u.v;
        }
        #pragma unroll
        for (int s = 0; s < 9; ++s) {
            const int r = 4 * wv - 5 + s;
            if (r >= 0 && r <= 25) {
                FragU u;
                #pragma unroll
                for (int i2 = 0; i2 < 4; ++i2)
                    u.u[i2] = Sh[LA + i2 * STRL + 16 * r];
                const bf16x8 af = u.v;
                #pragma unroll
                for (int pi = 0; pi < 4; ++pi) {
                    const int a = s - pi;
                    if (a >= 0 && a <= 5 && (4 * wv + pi) <= 30)
                        acc[pi][a] = __builtin_amdgcn_mfma_f32_16x16x32_bf16(af, bf[pi], acc[pi][a], 0, 0, 0);
                }
            }
        }

        lds_barrier();   // reads done before next stage overwrites
    }

    // ---- epilogue: 3 d-groups of 27; scatter->LDS, contiguous dwordx4 stores ----
    float* Shf = (float*)Sh;
    const float scale = 1.0f / 256.0f;
    float* outp = out + ((size_t)b * ND) * HW + (size_t)h * WSZ;

    for (int g = 0; g < 3; ++g) {
        const int d0 = 27 * g;

        #pragma unroll
        for (int pi = 0; pi < 4; ++pi) {
            const int p = 4 * wv + pi;
            #pragma unroll
            for (int a = 0; a < 6; ++a) {
                const int r = p - 5 + a;
                if (r >= 0 && r <= 25) {
                    const int j = 5 - a;
                    #pragma unroll
                    for (int rr = 0; rr < 4; ++rr) {
                        const int m = 4 * l4 + rr;
                        const int d = 16 * j + l15 - m;
                        if (d >= d0 && d < d0 + 27)
                            Shf[(d - d0) * ESTR + 16 * r + m] = acc[pi][a][rr] * scale;
                    }
                }
            }
        }
        lds_barrier();

        #pragma unroll
        for (int i = 0; i < 6; ++i) {
            const int idx = i * 512 + t;
            if (idx < 27 * 104) {
                const int d = idx / 104;
                const int q = idx - 104 * d;
                const f32x4 v = *(const f32x4*)&Shf[d * ESTR + 4 * q];
                *(f32x4*)(outp + (size_t)(d0 + d) * HW + 4 * q) = v;
            }
        }
        if (g < 2) lds_barrier();   // stores' LDS reads done before next scatter
    }
}

extern "C" void kernel_launch(void* const* d_in, const int* in_sizes, int n_in,
                              void* d_out, int out_size, void* d_ws, size_t ws_size,
                              hipStream_t stream) {
    const float* left  = (const float*)d_in[0];
    const float* right = (const float*)d_in[1];
    float* out = (float*)d_out;
    (void)in_sizes; (void)n_in; (void)out_size; (void)d_ws; (void)ws_size;
    corr_mfma_kernel<<<dim3(4 * 128), dim3(512), 0, stream>>>(left, right, out);
}

// Round 10
// 170.524 us; speedup vs baseline: 1.4714x; 1.4714x over previous
//
#include <hip/hip_runtime.h>
#include <hip/hip_bf16.h>
#include <stdint.h>

typedef __bf16 bf16x8 __attribute__((ext_vector_type(8)));
typedef float f32x4 __attribute__((ext_vector_type(4)));

#define MAXD 40
#define ND   81
#define CSZ  256
#define HSZ  128
#define WSZ  416
#define HW   (HSZ * WSZ)
#define NCHUNK 8

#define LSTR 448     // dwords per L channel row (416 data + shift + pad)
#define RSTR 544     // dwords per R channel row (496 data + shift + pad)
#define ROFF 14336   // dword offset of R region (= 32*448)
#define ESTR 420     // epilogue staging row stride (dwords)

// LDS-only drain barrier: global loads stay in flight across it (T4).
static __device__ __forceinline__ void lds_barrier() {
    asm volatile("s_waitcnt lgkmcnt(0)" ::: "memory");
    __builtin_amdgcn_s_barrier();
    __builtin_amdgcn_sched_barrier(0);
}

__global__ __launch_bounds__(1024, 4)
void corr_mfma_kernel(const float* __restrict__ left,
                      const float* __restrict__ right,
                      float* __restrict__ out) {
    __shared__ float Sh[31744];   // 126976 B: L[32][448] | R[32][544], fp32 [c][w]

    const int t   = threadIdx.x;
    const int wv  = t >> 6;      // 0..15
    const int l   = t & 63;
    const int l15 = l & 15;
    const int l4  = l >> 4;      // 0..3
    const int b   = blockIdx.x >> 7;
    const int h   = blockIdx.x & 127;

    const size_t slab = ((size_t)b * CSZ) * HW + (size_t)h * WSZ;
    const float* Lp = left  + slab;
    const float* Rp = right + slab;

    // ---- zero R halo cols once (u in [-40,0) and [416,456)) ----
    #pragma unroll
    for (int i = 0; i < 3; ++i) {
        const int idx = i * 1024 + t;        // 32c x 80 = 2560
        if (idx < 2560) {
            const int c = idx / 80;
            const int k = idx - 80 * c;
            const int col = (k < 40) ? k : (k + 416);
            Sh[ROFF + c * RSTR + 8 * ((c >> 3) & 3) + col] = 0.0f;
        }
    }

    // wave owns p-pair {p0, p0+1}; tile (pi,k): r = p0-5+pi+k, j = 5-k
    const int p0 = 2 * wv;               // 0..30
    const bool hasP1 = (p0 + 1 <= 30);   // wv=15 -> p1=31 masked

    f32x4 acc[2][6];
    #pragma unroll
    for (int pi = 0; pi < 2; ++pi)
        #pragma unroll
        for (int k = 0; k < 6; ++k)
            acc[pi][k] = (f32x4)0.0f;

    // fragment read bases (dwords): c = 8*l4 + kk, shift 8*l4
    const int LA = 3592 * l4 + l15;          // l4*(8*LSTR+8) + l15
    const int LB = ROFF + 4360 * l4 + l15;   // ROFF + l4*(8*RSTR+8) + l15

    f32x4 vL[4], vR[4];

    // ---- prologue: load + stage chunk 0 (contiguous 1KB runs per instr) ----
    #pragma unroll
    for (int i = 0; i < 4; ++i) {
        const int idx = i * 1024 + t;        // 32c x 104 quads = 3328
        if (idx < 3328) {
            const int c = idx / 104;
            const int q = idx - 104 * c;
            vL[i] = *(const f32x4*)(Lp + (size_t)c * HW + 4 * q);
            vR[i] = *(const f32x4*)(Rp + (size_t)c * HW + 4 * q);
        }
    }
    #pragma unroll
    for (int i = 0; i < 4; ++i) {
        const int idx = i * 1024 + t;
        if (idx < 3328) {
            const int c  = idx / 104;
            const int q  = idx - 104 * c;
            const int sh = 8 * ((c >> 3) & 3);
            *(f32x4*)&Sh[c * LSTR + sh + 4 * q]             = vL[i];
            *(f32x4*)&Sh[ROFF + c * RSTR + sh + 40 + 4 * q] = vR[i];
        }
    }
    lds_barrier();   // tile 0 + halo visible

    for (int ck = 0; ck < NCHUNK; ++ck) {
        const bool more = (ck + 1 < NCHUNK);

        // ---- A) issue next-chunk loads early (stay in flight across MFMA+barriers) ----
        if (more) {
            const float* Lc = Lp + (size_t)(ck + 1) * 32 * HW;
            const float* Rc = Rp + (size_t)(ck + 1) * 32 * HW;
            #pragma unroll
            for (int i = 0; i < 4; ++i) {
                const int idx = i * 1024 + t;
                if (idx < 3328) {
                    const int c = idx / 104;
                    const int q = idx - 104 * c;
                    vL[i] = *(const f32x4*)(Lc + (size_t)c * HW + 4 * q);
                    vR[i] = *(const f32x4*)(Rc + (size_t)c * HW + 4 * q);
                }
            }
        }

        // ---- B) banded MFMA: B-frags for p0,p1; 7 shared A-rows ----
        bf16x8 bfr[2];
        #pragma unroll
        for (int pi = 0; pi < 2; ++pi) {
            const int p  = p0 + pi;
            const int pc = (p > 30) ? 30 : p;
            #pragma unroll
            for (int kk = 0; kk < 8; ++kk)
                bfr[pi][kk] = (__bf16)Sh[LB + kk * RSTR + 16 * pc];
        }
        #pragma unroll
        for (int a = 0; a < 7; ++a) {
            const int r = p0 - 5 + a;
            if (r >= 0 && r <= 25) {
                bf16x8 af;
                #pragma unroll
                for (int kk = 0; kk < 8; ++kk)
                    af[kk] = (__bf16)Sh[LA + kk * LSTR + 16 * r];
                if (a < 6)
                    acc[0][a] = __builtin_amdgcn_mfma_f32_16x16x32_bf16(af, bfr[0], acc[0][a], 0, 0, 0);
                if (hasP1 && a >= 1)
                    acc[1][a - 1] = __builtin_amdgcn_mfma_f32_16x16x32_bf16(af, bfr[1], acc[1][a - 1], 0, 0, 0);
            }
        }

        if (more) {
            lds_barrier();   // all waves done reading tile ck

            // ---- C) LDS write of tile ck+1 (per-use vmcnt waits) ----
            #pragma unroll
            for (int i = 0; i < 4; ++i) {
                const int idx = i * 1024 + t;
                if (idx < 3328) {
                    const int c  = idx / 104;
                    const int q  = idx - 104 * c;
                    const int sh = 8 * ((c >> 3) & 3);
                    *(f32x4*)&Sh[c * LSTR + sh + 4 * q]             = vL[i];
                    *(f32x4*)&Sh[ROFF + c * RSTR + sh + 40 + 4 * q] = vR[i];
                }
            }

            lds_barrier();   // tile ck+1 visible
        }
    }

    lds_barrier();   // MFMA reads done; Sh free for epilogue staging

    // ---- epilogue: 3 d-groups of 27; scatter->LDS, contiguous f32x4 stores ----
    const float scale = 1.0f / 256.0f;
    float* outp = out + ((size_t)b * ND) * HW + (size_t)h * WSZ;

    for (int g = 0; g < 3; ++g) {
        const int d0 = 27 * g;

        // scatter: tile (pi,k): r = p0-5+pi+k, j = 5-k; d = 16j + l15 - m
        #pragma unroll
        for (int pi = 0; pi < 2; ++pi) {
            #pragma unroll
            for (int k = 0; k < 6; ++k) {
                const int r = p0 - 5 + pi + k;
                if (r >= 0 && r <= 25) {
                    const int j = 5 - k;
                    #pragma unroll
                    for (int rr = 0; rr < 4; ++rr) {
                        const int m = 4 * l4 + rr;
                        const int d = 16 * j + l15 - m;
                        if (d >= d0 && d < d0 + 27)
                            Sh[(d - d0) * ESTR + 16 * r + m] = acc[pi][k][rr] * scale;
                    }
                }
            }
        }
        lds_barrier();

        // contiguous stores: 27 x 104 quads = 2808 items
        #pragma unroll
        for (int i = 0; i < 3; ++i) {
            const int idx = i * 1024 + t;
            if (idx < 2808) {
                const int d = idx / 104;
                const int q = idx - 104 * d;
                const f32x4 v = *(const f32x4*)&Sh[d * ESTR + 4 * q];
                *(f32x4*)(outp + (size_t)(d0 + d) * HW + 4 * q) = v;
            }
        }
        if (g < 2) lds_barrier();   // store reads done before next scatter
    }
}

extern "C" void kernel_launch(void* const* d_in, const int* in_sizes, int n_in,
                              void* d_out, int out_size, void* d_ws, size_t ws_size,
                              hipStream_t stream) {
    const float* left  = (const float*)d_in[0];
    const float* right = (const float*)d_in[1];
    float* out = (float*)d_out;
    (void)in_sizes; (void)n_in; (void)out_size; (void)d_ws; (void)ws_size;
    corr_mfma_kernel<<<dim3(4 * 128), dim3(1024), 0, stream>>>(left, right, out);
}

// Round 11
// 101.585 us; speedup vs baseline: 2.4700x; 1.6786x over previous
//
#include <hip/hip_runtime.h>
#include <hip/hip_bf16.h>
#include <stdint.h>

typedef __bf16 bf16x8 __attribute__((ext_vector_type(8)));
typedef float f32x4 __attribute__((ext_vector_type(4)));

#define MAXD 40
#define ND   81
#define CSZ  256
#define HSZ  128
#define WSZ  416
#define HW   (HSZ * WSZ)

#define ALC  448        // dwords per channel row (416 data + 24 shift + pad)
#define EL   0          // even buf, L rows 0..15
#define ER   7168       // even buf, R rows
#define OL   14336      // odd buf, L
#define ORR  21504      // odd buf, R
#define ESTR 420        // epilogue row stride

union U8 { uint32_t u[4]; bf16x8 v; };

static __device__ __forceinline__ uint32_t pk2(float a, float b) {
    union { __bf16 h[2]; uint32_t u; } v;
    v.h[0] = (__bf16)a; v.h[1] = (__bf16)b;
    return v.u;
}

// async global->LDS, 16B/lane; LDS dst = wave-uniform base + lane*16
static __device__ __forceinline__ void gl16(const float* g, const float* l) {
    __builtin_amdgcn_global_load_lds(
        (const __attribute__((address_space(1))) void*)(uintptr_t)g,
        (__attribute__((address_space(3))) void*)(uint32_t)(uintptr_t)l,
        16, 0, 0);
}

static __device__ __forceinline__ void full_barrier() {
    asm volatile("s_waitcnt vmcnt(0) lgkmcnt(0)" ::: "memory");
    __builtin_amdgcn_s_barrier();
    __builtin_amdgcn_sched_barrier(0);
}

__global__ __launch_bounds__(1024)
void corr_mfma_kernel(const float* __restrict__ left,
                      const float* __restrict__ right,
                      float* __restrict__ out) {
    __shared__ float Sh[28672];   // 114688 B: E{L,R} | O{L,R}, fp32 [c][w]

    const int t   = threadIdx.x;
    const int wv  = t >> 6;      // 0..15
    const int l   = t & 63;
    const int l15 = l & 15;
    const int l4  = l >> 4;      // 0..3
    const int b   = blockIdx.x >> 7;
    const int h   = blockIdx.x & 127;

    const size_t slab = ((size_t)b * CSZ) * HW + (size_t)h * WSZ;
    // per-lane global staging addrs (wave wv stages channel c_local = wv)
    const float* gLw = left  + slab + (size_t)wv * HW + 4 * l;
    const float* gRw = right + slab + (size_t)wv * HW + 4 * l;
    // wave-uniform LDS row bases
    const int shw = 8 * ((wv >> 2) & 3);
    const float* dEL = &Sh[EL  + wv * ALC + shw];
    const float* dER = &Sh[ER  + wv * ALC + shw];
    const float* dOL = &Sh[OL  + wv * ALC + shw];
    const float* dOR = &Sh[ORR + wv * ALC + shw];

    // wave owns p-pair {p0, p0+1}
    const int p0 = 2 * wv;
    const bool hasP1 = (wv < 15);
    int  cb[2]; bool okb[2];
    #pragma unroll
    for (int pi = 0; pi < 2; ++pi) {
        const int u = 16 * (p0 + pi) - MAXD + l15;
        okb[pi] = ((unsigned)u < (unsigned)WSZ);
        cb[pi]  = okb[pi] ? u : 0;
    }
    const int FB = 1800 * l4;    // (4*l4)*448 + 8*l4, lane frag base

    f32x4 acc0[6], acc1[6];
    #pragma unroll
    for (int k = 0; k < 6; ++k) { acc0[k] = (f32x4)0.0f; acc1[k] = (f32x4)0.0f; }

    // ---- prologue: stage chunk 0 -> even buf ----
    {
        gl16(gLw, dEL); gl16(gRw, dER);
        if (l < 40) { gl16(gLw + 256, dEL + 256); gl16(gRw + 256, dER + 256); }
    }
    full_barrier();

    for (int m = 0; m < 8; ++m) {
        // ======== sub-phase A: stage chunk 2m+1 -> odd buf; read LO halves from even ========
        {
            const size_t co = (size_t)(2 * m + 1) * 16 * HW;
            gl16(gLw + co, dOL); gl16(gRw + co, dOR);
            if (l < 40) { gl16(gLw + co + 256, dOL + 256); gl16(gRw + co + 256, dOR + 256); }
        }
        uint2 aLo[7], bLo[2];
        #pragma unroll
        for (int pi = 0; pi < 2; ++pi) {
            if (pi == 0 || hasP1) {
                float v0 = Sh[ER + FB +   0 + cb[pi]];
                float v1 = Sh[ER + FB + 448 + cb[pi]];
                float v2 = Sh[ER + FB + 896 + cb[pi]];
                float v3 = Sh[ER + FB + 1344 + cb[pi]];
                if (!okb[pi]) { v0 = v1 = v2 = v3 = 0.0f; }
                bLo[pi] = make_uint2(pk2(v0, v1), pk2(v2, v3));
            } else bLo[pi] = make_uint2(0u, 0u);
        }
        #pragma unroll
        for (int a = 0; a < 7; ++a) {
            const int r = p0 - 5 + a;
            if (r >= 0 && r <= 25) {
                const int col = 16 * r + l15;
                const float v0 = Sh[EL + FB +   0 + col];
                const float v1 = Sh[EL + FB + 448 + col];
                const float v2 = Sh[EL + FB + 896 + col];
                const float v3 = Sh[EL + FB + 1344 + col];
                aLo[a] = make_uint2(pk2(v0, v1), pk2(v2, v3));
            } else aLo[a] = make_uint2(0u, 0u);
        }
        full_barrier();   // odd buf staged; everyone done reading even buf

        // ======== sub-phase B: stage chunk 2m+2 -> even buf; HI halves + MFMA ========
        if (m < 7) {
            const size_t co = (size_t)(2 * m + 2) * 16 * HW;
            gl16(gLw + co, dEL); gl16(gRw + co, dER);
            if (l < 40) { gl16(gLw + co + 256, dEL + 256); gl16(gRw + co + 256, dER + 256); }
        }
        bf16x8 bF[2];
        #pragma unroll
        for (int pi = 0; pi < 2; ++pi) {
            if (pi == 0 || hasP1) {
                float v0 = Sh[ORR + FB +   0 + cb[pi]];
                float v1 = Sh[ORR + FB + 448 + cb[pi]];
                float v2 = Sh[ORR + FB + 896 + cb[pi]];
                float v3 = Sh[ORR + FB + 1344 + cb[pi]];
                if (!okb[pi]) { v0 = v1 = v2 = v3 = 0.0f; }
                U8 x; x.u[0] = bLo[pi].x; x.u[1] = bLo[pi].y;
                x.u[2] = pk2(v0, v1); x.u[3] = pk2(v2, v3);
                bF[pi] = x.v;
            }
        }
        #pragma unroll
        for (int a = 0; a < 7; ++a) {
            const int r = p0 - 5 + a;
            if (r >= 0 && r <= 25) {
                const int col = 16 * r + l15;
                const float v0 = Sh[OL + FB +   0 + col];
                const float v1 = Sh[OL + FB + 448 + col];
                const float v2 = Sh[OL + FB + 896 + col];
                const float v3 = Sh[OL + FB + 1344 + col];
                U8 x; x.u[0] = aLo[a].x; x.u[1] = aLo[a].y;
                x.u[2] = pk2(v0, v1); x.u[3] = pk2(v2, v3);
                if (a < 6)
                    acc0[a] = __builtin_amdgcn_mfma_f32_16x16x32_bf16(x.v, bF[0], acc0[a], 0, 0, 0);
                if (hasP1 && a >= 1)
                    acc1[a - 1] = __builtin_amdgcn_mfma_f32_16x16x32_bf16(x.v, bF[1], acc1[a - 1], 0, 0, 0);
            }
        }
        full_barrier();   // even buf staged; everyone done reading odd buf
    }

    // ---- epilogue: 2 d-halves; scatter->LDS, contiguous f32x4 stores ----
    const float scale = 1.0f / 256.0f;
    float* outp = out + (size_t)b * ND * HW + (size_t)h * WSZ;

    #pragma unroll
    for (int gph = 0; gph < 2; ++gph) {
        const int d0 = gph * 41;
        const int dn = gph ? 40 : 41;

        #pragma unroll
        for (int pi = 0; pi < 2; ++pi) {
            if (pi == 0 || hasP1) {
                #pragma unroll
                for (int k = 0; k < 6; ++k) {
                    const int r = p0 - 5 + pi + k;
                    if (r >= 0 && r <= 25) {
                        const int j = 5 - k;
                        const f32x4 av = pi ? acc1[k] : acc0[k];
                        #pragma unroll
                        for (int rr = 0; rr < 4; ++rr) {
                            const int mm = 4 * l4 + rr;
                            const int d  = 16 * j + l15 - mm;
                            if ((unsigned)(d - d0) < (unsigned)dn)
                                Sh[(d - d0) * ESTR + 16 * r + mm] = av[rr] * scale;
                        }
                    }
                }
            }
        }
        full_barrier();

        #pragma unroll
        for (int i = 0; i < 5; ++i) {
            const int idx = i * 1024 + t;
            if (idx < dn * 104) {
                const int d = idx / 104;
                const int q = idx - 104 * d;
                *(f32x4*)(outp + (size_t)(d0 + d) * HW + 4 * q) = *(const f32x4*)&Sh[d * ESTR + 4 * q];
            }
        }
        if (gph == 0) full_barrier();
    }
}

extern "C" void kernel_launch(void* const* d_in, const int* in_sizes, int n_in,
                              void* d_out, int out_size, void* d_ws, size_t ws_size,
                              hipStream_t stream) {
    const float* left  = (const float*)d_in[0];
    const float* right = (const float*)d_in[1];
    float* out = (float*)d_out;
    (void)in_sizes; (void)n_in; (void)out_size; (void)d_ws; (void)ws_size;
    corr_mfma_kernel<<<dim3(4 * 128), dim3(1024), 0, stream>>>(left, right, out);
}